// Round 3
// baseline (84.258 us; speedup 1.0000x reference)
//
#include <hip/hip_runtime.h>

// ReverseCostExtractor, inverted (stream-maps) formulation.
// cost_maps: (B*H1*W1, 1, 64, 64) fp32, B=4 -> 16384 maps of 4096 floats.
// coords0/coords1: (B, 2, 64, 64) fp32.  out: (B, 81, 64, 64) fp32.
//
// Math per pixel p=(b,i,j):
//   F_p[e=(yy,xx)] = bilin(cost_maps[b,Y,X], coords1(p)),  (Y,X) = (y0i-4+yy, x0i-4+xx)
//   out[b, a*9+bb, i, j] = bilin over F_p at window pos from coords0(p) offsets
//
// R2: instead of 419M divergent lane-gathers (TA/random-line bound, R1 showed
// occupancy/MLP didn't help), stream every map ONCE coalesced into LDS and
// scatter F contributions to the ~100 pixels that need it (bin by floor(coords0)).

#define CAP 64          // bin capacity; Poisson(1) per cell, P[>=64] ~ 1e-90
#define FSTR 104        // padded LDS stride for F rows in K3

// ---- workspace layout (bytes) ----
#define OFF_CNT   0u            // 16384 * 4        = 65536
#define OFF_LIST  65536u        // 16384 * CAP * 4  = 4194304
#define OFF_POS   4259840u      // 16384 * 16       = 262144
#define OFF_WGT   4521984u      // 16384 * 16       = 262144
#define OFF_F     4784128u      // 16384 * 100 * 4  = 6553600   (total ~11.3 MB)

__global__ __launch_bounds__(256)
void k0_zero(int* __restrict__ cnt, float* __restrict__ F) {
    int t = blockIdx.x * 256 + threadIdx.x;
    if (t < 16384) cnt[t] = 0;
    for (int i = t; i < 16384 * 100; i += gridDim.x * 256) F[i] = 0.f;
}

__global__ __launch_bounds__(256)
void k1_setup(const float* __restrict__ coords0, const float* __restrict__ coords1,
              int* __restrict__ cnt, int* __restrict__ list,
              int4* __restrict__ pos, float4* __restrict__ wgt) {
    int pid = blockIdx.x * 256 + threadIdx.x;          // 0..16383
    int b   = pid >> 12;
    int cb  = b * 8192 + (pid & 4095);                 // (b,0,i,j); +4096 -> y

    // first sampler (coords1): corner positions + validity-folded weights
    float x1 = coords1[cb];
    float y1 = coords1[cb + 4096];
    float x1f = floorf(x1), y1f = floorf(y1);
    int   xi = (int)x1f,    yi = (int)y1f;
    float wx = x1 - x1f,    wy = y1 - y1f;
    int x0c = min(max(xi, 0), 63),     x1c = min(max(xi + 1, 0), 63);
    int y0c = min(max(yi, 0), 63),     y1c = min(max(yi + 1, 0), 63);
    float vx0 = ((unsigned)xi       < 64u) ? 1.f : 0.f;
    float vx1 = ((unsigned)(xi + 1) < 64u) ? 1.f : 0.f;
    float vy0 = ((unsigned)yi       < 64u) ? 1.f : 0.f;
    float vy1 = ((unsigned)(yi + 1) < 64u) ? 1.f : 0.f;
    pos[pid] = make_int4(y0c * 64 + x0c, y0c * 64 + x1c, y1c * 64 + x0c, y1c * 64 + x1c);
    wgt[pid] = make_float4((1.f - wy) * (1.f - wx) * vy0 * vx0,
                           (1.f - wy) * wx         * vy0 * vx1,
                           wy         * (1.f - wx) * vy1 * vx0,
                           wy         * wx         * vy1 * vx1);

    // bin by floor(coords0) cell
    float x0 = coords0[cb];
    float y0 = coords0[cb + 4096];
    int x0i = (int)floorf(x0);                         // in [0,63] (coords in [0,63])
    int y0i = (int)floorf(y0);
    int cell = (b << 12) | (y0i << 6) | x0i;
    int slot = atomicAdd(&cnt[cell], 1);
    if (slot < CAP) list[cell * CAP + slot] = pid;
}

__global__ __launch_bounds__(256, 8)
void k2_corr(const float* __restrict__ cost,
             const int* __restrict__ cnt, const int* __restrict__ list,
             const int4* __restrict__ pos, const float4* __restrict__ wgt,
             float* __restrict__ F) {
    const int bid = blockIdx.x;                        // (b<<12)|(Y<<6)|X == map index
    const int b = bid >> 12, Y = (bid >> 6) & 63, X = bid & 63;
    const int tid = threadIdx.x;

    __shared__ float s_map[4096];

    // stream the 16 KB map, coalesced
    const float4* m4 = (const float4*)(cost + (size_t)bid * 4096);
    float4 v[4];
#pragma unroll
    for (int k = 0; k < 4; ++k) v[k] = m4[tid + k * 256];

    // this thread's cell (threads 0..99)
    int n = 0, cell = 0, e = 0;
    if (tid < 100) {
        int dy = tid / 10, dx = tid - dy * 10;
        int cy = Y - 5 + dy, cx = X - 5 + dx;          // pixel cell (y0i,x0i)
        e = (9 - dy) * 10 + (9 - dx);                  // window entry this map fills
        if (((unsigned)cy < 64u) & ((unsigned)cx < 64u)) {
            cell = (b << 12) | (cy << 6) | cx;
            n = min(cnt[cell], CAP);
        }
    }

#pragma unroll
    for (int k = 0; k < 4; ++k) ((float4*)s_map)[tid + k * 256] = v[k];
    __syncthreads();

    for (int k = 0; k < n; ++k) {
        int   pid = list[cell * CAP + k];
        int4  P   = pos[pid];
        float4 Wt = wgt[pid];
        float f = Wt.x * s_map[P.x] + Wt.y * s_map[P.y]
                + Wt.z * s_map[P.z] + Wt.w * s_map[P.w];
        F[pid * 100 + e] = f;                          // unique (pid,e) -> no race
    }
}

__global__ __launch_bounds__(256)
void k3_out(const float* __restrict__ coords0, const float* __restrict__ F,
            float* __restrict__ out) {
    const int tid = threadIdx.x;
    const int P0  = blockIdx.x * 8;                    // 8 pixels, same (b,i)
    const int b = P0 >> 12, i = (P0 >> 6) & 63, j0 = P0 & 63;

    __shared__ int   s_rx[8][9], s_ry[8][9];
    __shared__ float s_fx[8][9], s_fy[8][9];
    __shared__ float s_F[8][FSTR];

    if (tid < 8) {
        int cb = b * 8192 + ((P0 + tid) & 4095);
        float x0 = coords0[cb];
        float y0 = coords0[cb + 4096];
        int x0i = (int)floorf(x0);
        int y0i = (int)floorf(y0);
#pragma unroll
        for (int a = 0; a < 9; ++a) {
            float Xv = x0 + (float)(a - 4);            // exact fp32 path of reference
            float Xf = floorf(Xv);
            s_rx[tid][a] = (int)Xf - (x0i - 4);        // 0..9 (10 on round-up, frac 0)
            s_fx[tid][a] = Xv - Xf;
            float Yv = y0 + (float)(a - 4);
            float Yf = floorf(Yv);
            s_ry[tid][a] = (int)Yf - (y0i - 4);
            s_fy[tid][a] = Yv - Yf;
        }
    }

    // stage F rows (coalesced 128B segments per pixel); OOB entries were pre-zeroed
    {
        int px = tid >> 5, l = tid & 31;
        const float* Fr = F + (size_t)(P0 + px) * 100;
        float t0 = Fr[l];
        float t1 = Fr[l + 32];
        float t2 = Fr[l + 64];
        float t3 = (l < 4) ? Fr[l + 96] : 0.f;
        s_F[px][l]      = t0;
        s_F[px][l + 32] = t1;
        s_F[px][l + 64] = t2;
        if (l < 4) s_F[px][l + 96] = t3;
    }
    __syncthreads();

    const int px  = tid & 7;
    const int chb = tid >> 3;                          // 0..31
    const size_t obase = (((size_t)b * 81) * 64 + i) * 64 + (size_t)(j0 + px);
#pragma unroll
    for (int r = 0; r < 3; ++r) {
        int ch = r * 32 + chb;
        if (ch < 81) {
            int a  = ch / 9;
            int bb = ch - a * 9;
            int   rx = s_rx[px][a];  float fx = s_fx[px][a];
            int   ry = s_ry[px][bb]; float fy = s_fy[px][bb];
            float f00 = (((unsigned)ry       < 10u) & ((unsigned)rx       < 10u)) ? s_F[px][ry * 10 + rx]           : 0.f;
            float f01 = (((unsigned)ry       < 10u) & ((unsigned)(rx + 1) < 10u)) ? s_F[px][ry * 10 + rx + 1]       : 0.f;
            float f10 = (((unsigned)(ry + 1) < 10u) & ((unsigned)rx       < 10u)) ? s_F[px][(ry + 1) * 10 + rx]     : 0.f;
            float f11 = (((unsigned)(ry + 1) < 10u) & ((unsigned)(rx + 1) < 10u)) ? s_F[px][(ry + 1) * 10 + rx + 1] : 0.f;
            float v = (1.f - fy) * ((1.f - fx) * f00 + fx * f01)
                    + fy         * ((1.f - fx) * f10 + fx * f11);
            out[obase + (size_t)ch * 4096] = v;
        }
    }
}

extern "C" void kernel_launch(void* const* d_in, const int* in_sizes, int n_in,
                              void* d_out, int out_size, void* d_ws, size_t ws_size,
                              hipStream_t stream) {
    const float* cost    = (const float*)d_in[0];
    const float* coords0 = (const float*)d_in[1];
    const float* coords1 = (const float*)d_in[2];
    float* out = (float*)d_out;

    char* ws = (char*)d_ws;
    int*    cnt  = (int*)   (ws + OFF_CNT);
    int*    list = (int*)   (ws + OFF_LIST);
    int4*   pos  = (int4*)  (ws + OFF_POS);
    float4* wgt  = (float4*)(ws + OFF_WGT);
    float*  F    = (float*) (ws + OFF_F);

    k0_zero <<<2048, 256, 0, stream>>>(cnt, F);
    k1_setup<<<64,   256, 0, stream>>>(coords0, coords1, cnt, list, pos, wgt);
    k2_corr <<<16384,256, 0, stream>>>(cost, cnt, list, pos, wgt, F);
    k3_out  <<<2048, 256, 0, stream>>>(coords0, F, out);
}

// Round 4
// 64.539 us; speedup vs baseline: 1.3055x; 1.3055x over previous
//
#include <hip/hip_runtime.h>

// ReverseCostExtractor: RAFT-style reverse correlation lookup.
// cost_maps: (B*H1*W1, 1, H2, W2) fp32, B=4, H=W=64
// coords0/coords1: (B, 2, 64, 64) fp32
// out: (B, 81, 64, 64) fp32
//
// Per pixel p=(b,i,j):
//   F_p[h1,w1] = bilin(cost_maps[b*4096 + h1*64+w1], at coords1[b,:,i,j])  (zero-pad)
//   out[b, a*9+bb, i, j] = bilin over F_p at (x0+(a-4), y0+(bb-4))  (zero-pad)
// Only a 10x10 window of F_p around floor(coords0) is ever touched.
//
// R3: gather version (R2's coalesced-stream inversion regressed: must move all
// 268 MB + F round trip). Bottleneck = divergent lane-request throughput, so
// fetch both x-corners of a row with ONE unaligned float2 load: 4 -> 2
// requests per map-visit (419M -> 210M lane requests).

#define PIX     8
#define THREADS 256
#define NTASK   (PIX * 100)                       // 800
#define NT      ((NTASK + THREADS - 1) / THREADS) // 4 rounds (last partial)
#define FSTRIDE 104

__global__ __launch_bounds__(THREADS, 8)
void rce_kernel(const float* __restrict__ cost,
                const float* __restrict__ coords0,
                const float* __restrict__ coords1,
                float* __restrict__ out) {
    const int tid = threadIdx.x;
    const int P   = blockIdx.x * PIX;     // first pixel index (b*64+i)*64+j0
    const int b   = P >> 12;
    const int i   = (P >> 6) & 63;
    const int j0  = P & 63;

    __shared__ int   s_row0[PIX], s_row1[PIX];     // pair-load base offsets (y*64+xb)
    __shared__ int   s_selhi[PIX], s_sello[PIX];   // corner-from-pair selectors
    __shared__ float s_w[PIX][4];                  // validity-folded bilinear weights
    __shared__ int   s_x0i[PIX], s_y0i[PIX];
    __shared__ int   s_rx[PIX][9], s_ry[PIX][9];   // window-relative corner idx per offset
    __shared__ float s_fx[PIX][9], s_fy[PIX][9];   // fractional weights per offset
    __shared__ float s_F[PIX][FSTRIDE];            // 10x10 F window

    // ---- Phase 1: per-pixel params (PIX threads) ----
    if (tid < PIX) {
        const int j = j0 + tid;
        const int cbase = (b * 2) * 4096 + i * 64 + j;   // (b,0,i,j); +4096 -> (b,1,i,j)

        // first sampler (coords1): pair-load bases + selectors + weights
        float x1 = coords1[cbase];
        float y1 = coords1[cbase + 4096];
        float x1f = floorf(x1), y1f = floorf(y1);
        int   xi = (int)x1f,    yi = (int)y1f;
        float wx = x1 - x1f,    wy = y1 - y1f;
        int xb  = min(max(xi, 0), 62);             // pair [xb, xb+1] always in-bounds
        int y0c = min(max(yi, 0), 63), y1c = min(max(yi + 1, 0), 63);
        float vx0 = ((unsigned)xi       < 64u) ? 1.f : 0.f;
        float vx1 = ((unsigned)(xi + 1) < 64u) ? 1.f : 0.f;
        float vy0 = ((unsigned)yi       < 64u) ? 1.f : 0.f;
        float vy1 = ((unsigned)(yi + 1) < 64u) ? 1.f : 0.f;
        s_row0[tid]  = y0c * 64 + xb;
        s_row1[tid]  = y1c * 64 + xb;
        s_selhi[tid] = (xi >= 63);                 // corner x0c == xb+1 (clamped high)
        s_sello[tid] = (xi <= -1);                 // corner x1c == xb   (clamped low)
        s_w[tid][0] = (1.f - wy) * (1.f - wx) * vy0 * vx0;
        s_w[tid][1] = (1.f - wy) * wx         * vy0 * vx1;
        s_w[tid][2] = wy         * (1.f - wx) * vy1 * vx0;
        s_w[tid][3] = wy         * wx         * vy1 * vx1;

        // second sampler (coords0): per-axis offset params, exact fp32 floor per channel
        float x0 = coords0[cbase];
        float y0 = coords0[cbase + 4096];
        int x0i = (int)floorf(x0);
        int y0i = (int)floorf(y0);
        s_x0i[tid] = x0i;
        s_y0i[tid] = y0i;
#pragma unroll
        for (int a = 0; a < 9; ++a) {
            float X  = x0 + (float)(a - 4);        // matches ref: centroid + delta in fp32
            float Xf = floorf(X);
            s_rx[tid][a] = (int)Xf - (x0i - 4);    // window-relative; 0..10 (round-up -> frac 0)
            s_fx[tid][a] = X - Xf;
            float Y  = y0 + (float)(a - 4);
            float Yf = floorf(Y);
            s_ry[tid][a] = (int)Yf - (y0i - 4);
            s_fy[tid][a] = Y - Yf;
        }
    }
    __syncthreads();

    // ---- Phase 2: stage F window (PIX px x 100 entries) ----
    // Hoist ALL pair-loads (2 per task, 8 in flight per thread), then consume.
    const float* cmb = cost + (size_t)b * 4096 * 4096;
    float2 v0[NT], v1[NT];
#pragma unroll
    for (int it = 0; it < NT; ++it) {
        int task = it * THREADS + tid;
        int t  = (task < NTASK) ? task : 0;
        int px = t & (PIX - 1);
        int e  = t / PIX;                  // 0..99
        int yy = e / 10;
        int xx = e - yy * 10;
        int X = s_x0i[px] - 4 + xx;
        int Y = s_y0i[px] - 4 + yy;
        bool wok = ((unsigned)X < 64u) & ((unsigned)Y < 64u);
        const float* map = cmb + ((size_t)(wok ? (Y * 64 + X) : 0) << 12);
        v0[it] = *(const float2*)(map + s_row0[px]);   // unaligned ok on CDNA
        v1[it] = *(const float2*)(map + s_row1[px]);
    }
#pragma unroll
    for (int it = 0; it < NT; ++it) {
        int task = it * THREADS + tid;
        if (task < NTASK) {
            int px = task & (PIX - 1);
            int e  = task / PIX;
            int yy = e / 10;
            int xx = e - yy * 10;
            int X = s_x0i[px] - 4 + xx;
            int Y = s_y0i[px] - 4 + yy;
            bool wok  = ((unsigned)X < 64u) & ((unsigned)Y < 64u);
            bool shi  = s_selhi[px] != 0;
            bool slo  = s_sello[px] != 0;
            float V00 = shi ? v0[it].y : v0[it].x;     // (y0c, x0c)
            float V01 = slo ? v0[it].x : v0[it].y;     // (y0c, x1c)
            float V10 = shi ? v1[it].y : v1[it].x;     // (y1c, x0c)
            float V11 = slo ? v1[it].x : v1[it].y;     // (y1c, x1c)
            float F = s_w[px][0] * V00 + s_w[px][1] * V01
                    + s_w[px][2] * V10 + s_w[px][3] * V11;
            s_F[px][e] = wok ? F : 0.f;
        }
    }
    __syncthreads();

    // ---- Phase 3: 81 outputs per pixel, coalesced writes ----
    const int px  = tid & (PIX - 1);
    const int chb = tid / PIX;                     // 0..31
    const size_t obase = (((size_t)b * 81) * 64 + i) * 64 + (size_t)(j0 + px);
#pragma unroll
    for (int it = 0; it < 3; ++it) {
        int ch = it * (THREADS / PIX) + chb;
        if (ch < 81) {
            int a  = ch / 9;
            int bb = ch - a * 9;
            int   rx = s_rx[px][a];  float fx = s_fx[px][a];
            int   ry = s_ry[px][bb]; float fy = s_fy[px][bb];
            float f00 = (((unsigned)ry       < 10u) & ((unsigned)rx       < 10u)) ? s_F[px][ry * 10 + rx]           : 0.f;
            float f01 = (((unsigned)ry       < 10u) & ((unsigned)(rx + 1) < 10u)) ? s_F[px][ry * 10 + rx + 1]       : 0.f;
            float f10 = (((unsigned)(ry + 1) < 10u) & ((unsigned)rx       < 10u)) ? s_F[px][(ry + 1) * 10 + rx]     : 0.f;
            float f11 = (((unsigned)(ry + 1) < 10u) & ((unsigned)(rx + 1) < 10u)) ? s_F[px][(ry + 1) * 10 + rx + 1] : 0.f;
            float v = (1.f - fy) * ((1.f - fx) * f00 + fx * f01)
                    + fy         * ((1.f - fx) * f10 + fx * f11);
            out[obase + (size_t)ch * 4096] = v;
        }
    }
}

extern "C" void kernel_launch(void* const* d_in, const int* in_sizes, int n_in,
                              void* d_out, int out_size, void* d_ws, size_t ws_size,
                              hipStream_t stream) {
    const float* cost    = (const float*)d_in[0];
    const float* coords0 = (const float*)d_in[1];
    const float* coords1 = (const float*)d_in[2];
    float* out = (float*)d_out;

    const int total_px = 4 * 64 * 64;              // 16384
    dim3 grid(total_px / PIX), block(THREADS);
    rce_kernel<<<grid, block, 0, stream>>>(cost, coords0, coords1, out);
}